// Round 14
// baseline (1213.811 us; speedup 1.0000x reference)
//
#include <hip/hip_runtime.h>
#include <math.h>

// Problem constants (B=2, H=16, L=2048, D=128, fp32 in/out, int32 mask)
constexpr int Bc_ = 2;
constexpr int Hc_ = 16;
constexpr int Lc_ = 2048;
constexpr int Dc_ = 128;
constexpr int BR  = 128;  // Q rows per block (4 waves x 32 rows, 32x32 MFMA)
constexpr int BC  = 32;   // K rows per tile
// 1/sqrt(128) * log2(e): exp(x) == exp2(x*log2e); fold log2e into Q pre-scale.
constexpr float SCALE_LOG2E = 0.08838834764831845f * 1.4426950408889634f;

typedef __attribute__((ext_vector_type(8)))  short        bf16x8;
typedef __attribute__((ext_vector_type(4)))  float        f32x4;
typedef __attribute__((ext_vector_type(16))) float        f32x16;
typedef __attribute__((ext_vector_type(4)))  int          i32x4;
typedef __attribute__((ext_vector_type(4)))  unsigned int u32x4;

__device__ __forceinline__ unsigned short f2bf(float f) {
  unsigned u = __builtin_bit_cast(unsigned, f);
  return (unsigned short)((u + 0x7fffu + ((u >> 16) & 1u)) >> 16);
}

__device__ __forceinline__ unsigned cvt_pk_bf16(float lo, float hi) {
  unsigned r;
  asm("v_cvt_pk_bf16_f32 %0, %1, %2" : "=v"(r) : "v"(lo), "v"(hi));
  return r;
}

// Workgroup barrier that does NOT drain vmcnt (unlike __syncthreads).
__device__ __forceinline__ void barrier_lgkm() {
  asm volatile("s_waitcnt lgkmcnt(0)\n\ts_barrier" ::: "memory");
}

constexpr int KS_STRIDE = 136;  // K tile rows (shorts)
constexpr int VT_STRIDE = 40;   // V^T rows (shorts, 32 k-cols + 8 pad)

// XOR swizzle (shorts), write==read, bijective, 16B-preserving (R7-verified).
__device__ __forceinline__ int swz(int row, int colShorts) {
  return colShorts ^ (((row >> 3) & 3) << 3);
}

// ===========================================================================
// R14 = R11/R13 structure + D-SPLIT x2 (the only occupancy path compatible
// with the measured register wall).
// Wall: >2 waves/EU needs live set <= ~168; R13's demand = acc 64 + ~136 =
// ~200 -> spill (R3/R12, measured). D-split halves acc (64->32) and vr
// (16->8): demand ~155 < 168 -> (256,3) should NOT spill.
// Each block computes output dims [dh*64, dh*64+64): QK^T + softmax are
// recomputed redundantly per half (MFMA 8%, VALU 13% busy - free headroom);
// V staging/PV/epilogue halve. lsum identical in both halves -> each
// normalizes itself; disjoint output ranges -> NO merge, NO workspace.
// Decode pairs both halves of a (bh,qblk) on the SAME XCD (ids 8 apart) so
// the twin's mask/K/Q reads hit L2/L3.
// Grid 1024, 3 blocks/CU resident -> 12 waves/CU (1.5x latency hiding).
// Tile math byte-identical to R11 (verified) except PV/Vt index ranges.
// ===========================================================================
#define TILE_BODY(KB, MC, MN)                                               \
  {                                                                         \
    /* 1. stage current K regs -> LDS (bf16, swizzled row-major) */         \
    {                                                                       \
      u32x4 a, b;                                                           \
      a[0] = cvt_pk_bf16(kr[0][0], kr[0][1]);                               \
      a[1] = cvt_pk_bf16(kr[0][2], kr[0][3]);                               \
      a[2] = cvt_pk_bf16(kr[1][0], kr[1][1]);                               \
      a[3] = cvt_pk_bf16(kr[1][2], kr[1][3]);                               \
      b[0] = cvt_pk_bf16(kr[2][0], kr[2][1]);                               \
      b[1] = cvt_pk_bf16(kr[2][2], kr[2][3]);                               \
      b[2] = cvt_pk_bf16(kr[3][0], kr[3][1]);                               \
      b[3] = cvt_pk_bf16(kr[3][2], kr[3][3]);                               \
      *(u32x4*)&Ks[krow * KS_STRIDE + swz(krow, kcg * 16)]     = a;         \
      *(u32x4*)&Ks[krow * KS_STRIDE + swz(krow, kcg * 16 + 8)] = b;         \
    }                                                                       \
    /* stage this block's 64 V d-cols -> LDS transposed (swizzled) */       \
    {                                                                       \
      const unsigned w0 = cvt_pk_bf16(vr[0][0], vr[0][1]);                  \
      const unsigned w1 = cvt_pk_bf16(vr[0][2], vr[0][3]);                  \
      const unsigned w2 = cvt_pk_bf16(vr[1][0], vr[1][1]);                  \
      const unsigned w3 = cvt_pk_bf16(vr[1][2], vr[1][3]);                  \
      const int d0 = vcg4 * 8;                                              \
      Vt[(d0 + 0) * VT_STRIDE + swz(d0 + 0, vrow)] = (unsigned short)w0;    \
      Vt[(d0 + 1) * VT_STRIDE + swz(d0 + 1, vrow)] = (unsigned short)(w0 >> 16); \
      Vt[(d0 + 2) * VT_STRIDE + swz(d0 + 2, vrow)] = (unsigned short)w1;    \
      Vt[(d0 + 3) * VT_STRIDE + swz(d0 + 3, vrow)] = (unsigned short)(w1 >> 16); \
      Vt[(d0 + 4) * VT_STRIDE + swz(d0 + 4, vrow)] = (unsigned short)w2;    \
      Vt[(d0 + 5) * VT_STRIDE + swz(d0 + 5, vrow)] = (unsigned short)(w2 >> 16); \
      Vt[(d0 + 6) * VT_STRIDE + swz(d0 + 6, vrow)] = (unsigned short)w3;    \
      Vt[(d0 + 7) * VT_STRIDE + swz(d0 + 7, vrow)] = (unsigned short)(w3 >> 16); \
    }                                                                       \
    /* 2. issue next-tile K/V + mask loads (1-deep, cacheable) */           \
    {                                                                       \
      const int kbn = ((KB) + BC) & (Lc_ - 1);                              \
      const float* kp = kbase_g + (size_t)kbn * Dc_;                        \
      const float* vp = vbase_g + (size_t)kbn * Dc_;                        \
      kr[0] = *(const f32x4*)(kp + 0);  kr[1] = *(const f32x4*)(kp + 4);    \
      kr[2] = *(const f32x4*)(kp + 8);  kr[3] = *(const f32x4*)(kp + 12);   \
      vr[0] = *(const f32x4*)(vp + 0);  vr[1] = *(const f32x4*)(vp + 4);    \
      MN##0 = *(const i32x4*)(mbase_g + kbn);                               \
      MN##1 = *(const i32x4*)(mbase_g + kbn + 8);                           \
      MN##2 = *(const i32x4*)(mbase_g + kbn + 16);                          \
      MN##3 = *(const i32x4*)(mbase_g + kbn + 24);                          \
    }                                                                       \
    /* 3. barrier (lgkm only) — publishes Ks/Vt */                          \
    barrier_lgkm();                                                         \
    /* 4. S^T = K (Q*scale)^T : 8 MFMAs as TWO independent 4-chains */      \
    f32x16 s0 = (f32x16)0.0f, s1 = (f32x16)0.0f;                            \
    __builtin_amdgcn_s_setprio(1);                                          \
    _Pragma("unroll")                                                       \
    for (int st = 0; st < 8; st += 2) {                                     \
      const bf16x8 kf0 = *(const bf16x8*)&Ks[l31 * KS_STRIDE + swz(l31, st * 16 + hi8)]; \
      s0 = __builtin_amdgcn_mfma_f32_32x32x16_bf16(kf0, qf[st], s0, 0, 0, 0); \
      const bf16x8 kf1 = *(const bf16x8*)&Ks[l31 * KS_STRIDE + swz(l31, (st + 1) * 16 + hi8)]; \
      s1 = __builtin_amdgcn_mfma_f32_32x32x16_bf16(kf1, qf[st + 1], s1, 0, 0, 0); \
    }                                                                       \
    __builtin_amdgcn_s_setprio(0);                                          \
    const f32x16 s = s0 + s1;                                               \
    /* 5. p = mask ? exp2(s) : 0 ; scalar row-sum; PV A-frags in register */\
    bf16x8 pa0, pa1;                                                        \
    {                                                                       \
      const float p0  = ((MC##0)[0] != 0) ? exp2f(s[0])  : 0.0f;            \
      const float p1  = ((MC##0)[1] != 0) ? exp2f(s[1])  : 0.0f;            \
      const float p2  = ((MC##0)[2] != 0) ? exp2f(s[2])  : 0.0f;            \
      const float p3  = ((MC##0)[3] != 0) ? exp2f(s[3])  : 0.0f;            \
      const float p4  = ((MC##1)[0] != 0) ? exp2f(s[4])  : 0.0f;            \
      const float p5  = ((MC##1)[1] != 0) ? exp2f(s[5])  : 0.0f;            \
      const float p6  = ((MC##1)[2] != 0) ? exp2f(s[6])  : 0.0f;            \
      const float p7  = ((MC##1)[3] != 0) ? exp2f(s[7])  : 0.0f;            \
      const float p8  = ((MC##2)[0] != 0) ? exp2f(s[8])  : 0.0f;            \
      const float p9  = ((MC##2)[1] != 0) ? exp2f(s[9])  : 0.0f;            \
      const float p10 = ((MC##2)[2] != 0) ? exp2f(s[10]) : 0.0f;            \
      const float p11 = ((MC##2)[3] != 0) ? exp2f(s[11]) : 0.0f;            \
      const float p12 = ((MC##3)[0] != 0) ? exp2f(s[12]) : 0.0f;            \
      const float p13 = ((MC##3)[1] != 0) ? exp2f(s[13]) : 0.0f;            \
      const float p14 = ((MC##3)[2] != 0) ? exp2f(s[14]) : 0.0f;            \
      const float p15 = ((MC##3)[3] != 0) ? exp2f(s[15]) : 0.0f;            \
      lsum += (((p0 + p1) + (p2 + p3)) + ((p4 + p5) + (p6 + p7)))           \
            + (((p8 + p9) + (p10 + p11)) + ((p12 + p13) + (p14 + p15)));    \
      const unsigned c0 = cvt_pk_bf16(p0,  p1),  c1 = cvt_pk_bf16(p2,  p3); \
      const unsigned c2 = cvt_pk_bf16(p4,  p5),  c3 = cvt_pk_bf16(p6,  p7); \
      const unsigned c4 = cvt_pk_bf16(p8,  p9),  c5 = cvt_pk_bf16(p10, p11);\
      const unsigned c6 = cvt_pk_bf16(p12, p13), c7 = cvt_pk_bf16(p14, p15);\
      const unsigned x0 = (unsigned)__shfl_xor((int)c0, 32);                \
      const unsigned x1 = (unsigned)__shfl_xor((int)c1, 32);                \
      const unsigned x2 = (unsigned)__shfl_xor((int)c2, 32);                \
      const unsigned x3 = (unsigned)__shfl_xor((int)c3, 32);                \
      const unsigned x4 = (unsigned)__shfl_xor((int)c4, 32);                \
      const unsigned x5 = (unsigned)__shfl_xor((int)c5, 32);                \
      const unsigned x6 = (unsigned)__shfl_xor((int)c6, 32);                \
      const unsigned x7 = (unsigned)__shfl_xor((int)c7, 32);                \
      u32x4 a0, a1;                                                         \
      a0[0] = lo ? c0 : x2;  a0[1] = lo ? c1 : x3;                          \
      a0[2] = lo ? x0 : c2;  a0[3] = lo ? x1 : c3;                          \
      a1[0] = lo ? c4 : x6;  a1[1] = lo ? c5 : x7;                          \
      a1[2] = lo ? x4 : c6;  a1[3] = lo ? x5 : c7;                          \
      pa0 = __builtin_bit_cast(bf16x8, a0);                                 \
      pa1 = __builtin_bit_cast(bf16x8, a1);                                 \
    }                                                                       \
    /* 6. O += P V : this block's 2 d-blocks x 2 k-halves */                \
    __builtin_amdgcn_s_setprio(1);                                          \
    _Pragma("unroll")                                                       \
    for (int nb = 0; nb < 2; ++nb) {                                        \
      const int vrw0 = nb * 32 + l31;                                       \
      const bf16x8 vf0 = *(const bf16x8*)&Vt[vrw0 * VT_STRIDE + swz(vrw0, hi8)]; \
      acc[nb] = __builtin_amdgcn_mfma_f32_32x32x16_bf16(pa0, vf0, acc[nb], 0, 0, 0); \
      const bf16x8 vf1 = *(const bf16x8*)&Vt[vrw0 * VT_STRIDE + swz(vrw0, 16 + hi8)]; \
      acc[nb] = __builtin_amdgcn_mfma_f32_32x32x16_bf16(pa1, vf1, acc[nb], 0, 0, 0); \
    }                                                                       \
    __builtin_amdgcn_s_setprio(0);                                          \
    /* 7. protect LDS before next overwrite */                              \
    barrier_lgkm();                                                         \
  }

// launch_bounds(256,3): cap ~168 regs/wave. Demand ~155 (qf 32 + acc 32 +
// kr 16 + vr 8 + masks 32 + temps) — below cap, unlike both prior (256,3)
// spills (R3/R12 at ~200 demand with acc=64). 4 waves/EU stays forbidden
// (cap 128 -> 2.5 GB spill, measured twice).
// Grid 1024, 3 blocks/CU resident. LDS: Ks 8704 + Vt 64*40*2=5120 = 13824 B.
__global__ __launch_bounds__(256, 3) void attn_fwd(
    const float* __restrict__ Q, const float* __restrict__ K,
    const float* __restrict__ V, const int* __restrict__ Mask,
    float* __restrict__ Out) {
  // Decode: xcd = id&7 (HW round-robin), both D-halves of a (bh,qblk) have
  // ids 8 apart -> same XCD, near-simultaneous dispatch -> shared mask/K/Q
  // lines hit L2/L3. Each XCD owns 4 bh (K/V L2-resident; R10: FETCH -40%).
  const int id   = blockIdx.x;
  const int xcd  = id & 7;
  const int sub  = id >> 3;          // 0..127
  const int bh   = xcd * 4 + (sub >> 5);
  const int rem  = sub & 31;
  const int qblk = rem >> 1;
  const int dh   = rem & 1;          // which 64-dim output half

  const int tid  = threadIdx.x;
  const int w    = tid >> 6;
  const int lane = tid & 63;
  const int l31  = lane & 31;
  const int hi   = lane >> 5;
  const int hi8  = hi * 8;
  const bool lo  = (hi == 0);

  const float* Qg = Q + (size_t)bh * Lc_ * Dc_;
  const float* Kg = K + (size_t)bh * Lc_ * Dc_;
  const float* Vg = V + (size_t)bh * Lc_ * Dc_;
  const int*   Mg = Mask + (size_t)bh * Lc_ * Lc_;
  float*       Og = Out + (size_t)bh * Lc_ * Dc_;

  const int qr0 = qblk * BR + w * 32;

  __shared__ alignas(16) unsigned short Ks[BC * KS_STRIDE];
  __shared__ alignas(16) unsigned short Vt[64 * VT_STRIDE];

  // ---- Q fragments (B-operand of 32x32x16), full D, loaded once ----
  bf16x8 qf[8];
  {
    const float* qrow = Qg + (size_t)(qr0 + l31) * Dc_ + hi8;
#pragma unroll
    for (int st = 0; st < 8; ++st) {
      const f32x4 a = *(const f32x4*)(qrow + st * 16);
      const f32x4 b = *(const f32x4*)(qrow + st * 16 + 4);
      bf16x8 f;
      f[0] = (short)f2bf(a[0] * SCALE_LOG2E); f[1] = (short)f2bf(a[1] * SCALE_LOG2E);
      f[2] = (short)f2bf(a[2] * SCALE_LOG2E); f[3] = (short)f2bf(a[3] * SCALE_LOG2E);
      f[4] = (short)f2bf(b[0] * SCALE_LOG2E); f[5] = (short)f2bf(b[1] * SCALE_LOG2E);
      f[6] = (short)f2bf(b[2] * SCALE_LOG2E); f[7] = (short)f2bf(b[3] * SCALE_LOG2E);
      qf[st] = f;
    }
  }

  f32x16 acc[2];
#pragma unroll
  for (int i = 0; i < 2; ++i) acc[i] = (f32x16)0.0f;
  float lsum = 0.0f;

  // K staging: unchanged (32 rows x 128 cols). V staging: 32 k-rows x this
  // block's 64 d-cols; thread -> (k-row vrow, 8 d-cols at vcg4*8).
  const int krow = tid >> 3;   // 0..31
  const int kcg  = tid & 7;
  const int vrow = tid & 31;   // k-row
  const int vcg4 = tid >> 5;   // 0..7 -> d-col group of 8

  const float* kbase_g = Kg + (size_t)krow * Dc_ + kcg * 16;
  const float* vbase_g = Vg + (size_t)vrow * Dc_ + dh * 64 + vcg4 * 8;
  const int*   mbase_g = Mg + (size_t)(qr0 + l31) * Lc_ + hi * 4;

  f32x4 kr[4], vr[2];
  i32x4 mA0, mA1, mA2, mA3, mB0, mB1, mB2, mB3;

  kr[0] = *(const f32x4*)(kbase_g + 0);  kr[1] = *(const f32x4*)(kbase_g + 4);
  kr[2] = *(const f32x4*)(kbase_g + 8);  kr[3] = *(const f32x4*)(kbase_g + 12);
  vr[0] = *(const f32x4*)(vbase_g + 0);  vr[1] = *(const f32x4*)(vbase_g + 4);
  mA0 = *(const i32x4*)(mbase_g);
  mA1 = *(const i32x4*)(mbase_g + 8);
  mA2 = *(const i32x4*)(mbase_g + 16);
  mA3 = *(const i32x4*)(mbase_g + 24);

#pragma unroll 1
  for (int kb = 0; kb < Lc_; kb += 2 * BC) {
    TILE_BODY(kb,      mA, mB)
    TILE_BODY(kb + BC, mB, mA)
  }

  // ---- epilogue: combine k-halves' sums, normalize, store this half ----
  lsum += __shfl_xor(lsum, 32);
  const float inv = 1.0f / lsum;
#pragma unroll
  for (int r = 0; r < 16; ++r) {
    const int qrow_r = (r & 3) + 8 * (r >> 2) + 4 * hi;
    const float rinv = __shfl(inv, qrow_r);
    float* orow = Og + (size_t)(qr0 + qrow_r) * Dc_ + dh * 64 + l31;
    __builtin_nontemporal_store(acc[0][r] * rinv, orow);
    __builtin_nontemporal_store(acc[1][r] * rinv, orow + 32);
  }
}

extern "C" void kernel_launch(void* const* d_in, const int* in_sizes, int n_in,
                              void* d_out, int out_size, void* d_ws, size_t ws_size,
                              hipStream_t stream) {
  const float* Q    = (const float*)d_in[0];
  const float* K    = (const float*)d_in[1];
  const float* V    = (const float*)d_in[2];
  const int*   Mask = (const int*)d_in[3];
  float*       Out  = (float*)d_out;
  (void)d_ws; (void)ws_size;
  attn_fwd<<<dim3(1024), dim3(256), 0, stream>>>(Q, K, V, Mask, Out);
}